// Round 8
// baseline (242.731 us; speedup 1.0000x reference)
//
#include <hip/hip_runtime.h>

#define BLOCK 256
#define RPB (2*BLOCK)          // 512 rows per block, adjacent pair per thread
// R8: LDS-staged input path. R3's true profile (correcting the ~2x-inflated
// VALUBusy derived counter for SIMD-32) is ~13us VALU / ~42us stall. The stall
// is L2 request amplification: 22 scalar dword loads at 44B stride -> each
// vmem inst touches ~22 cache lines for a wave, ~500 line-requests per wave vs
// 44 unique (11x). Fix: block stages its 512 contiguous rows (22528B) into LDS
// with float4 chunk loads (64 lanes x consecutive 16B = minimal requests),
// then each thread ds_read2's its adjacent row pair. Outputs of adjacent rows
// are 6 contiguous floats -> 3 aligned float2 stores.
// FMA stream is R3 verbatim: packed v2f, weights pre-duplicated {w,w} in d_ws
// (uniform s_load_dwordx2 -> SGPR pair -> legal VOP3P src; R7 confirmed a lone
// 32-bit SGPR is NOT a legal VOP3P operand). Locals stay in the proven
// <=16-element constant-indexed SROA class (R1/R4: bigger -> scratch).

typedef float v2f __attribute__((ext_vector_type(2)));

struct WPtrs {
    const float* w[19];
    const float* b[19];
};

struct WDup {            // pointers into d_ws: duplicated {v,v} pairs
    const v2f* w[19];
    const v2f* b[19];
};

enum LId {FU1,FU2,KU1,KU2,HU1,HU2,MD1,MD2,MD3,HD1,HD2,KD1,KD2,HA1,HA2,KA1,KA2,FA1,FA2};

__constant__ const int kWN[19] = {4,4,16,16,36,36,176,256,96,24,16,8,4,32,4,24,4,16,4};
__constant__ const int kBN[19] = {2,2,4,4,6,6,16,16,6,4,4,2,2,4,1,4,1,4,1};

// ---- prep: duplicate weights+biases into ws as {v,v}; one block per layer ----
__global__ void prep_kernel(WPtrs P, float* __restrict__ ws) {
    const int l = blockIdx.x;
    const int t = threadIdx.x;
    int off = 0;
    for (int i = 0; i < l; ++i) off += 2 * (kWN[i] + kBN[i]);
    float* dw = ws + off;
    const int wn = kWN[l];
    for (int i = t; i < wn; i += BLOCK) {
        const float v = P.w[l][i];
        dw[2*i] = v; dw[2*i+1] = v;
    }
    float* db = dw + 2*wn;
    const int bn = kBN[l];
    for (int i = t; i < bn; i += BLOCK) {
        const float v = P.b[l][i];
        db[2*i] = v; db[2*i+1] = v;
    }
}

template<int DIN,int DOUT,bool RELU>
__device__ __forceinline__ void lin2(const v2f (&in)[DIN], v2f (&out)[DOUT],
                                     const v2f* __restrict__ wd, const v2f* __restrict__ bd) {
#pragma unroll
    for (int j = 0; j < DOUT; ++j) {
        v2f acc = bd[j];                          // {b,b}: SGPR pair
#pragma unroll
        for (int i = 0; i < DIN; ++i)
            acc = __builtin_elementwise_fma(in[i], wd[i*DOUT + j], acc); // v_pk_fma_f32
        if (RELU) {
            const v2f z = {0.0f, 0.0f};
            acc = __builtin_elementwise_max(acc, z);                     // v_pk_max_f32
        }
        out[j] = acc;
    }
}

__global__ __launch_bounds__(BLOCK) void pnet_kernel(
    const float* __restrict__ x, float* __restrict__ out, int B, WDup P) {
    const int tid = threadIdx.x;
    const long long rowBase = (long long)blockIdx.x * RPB;
    const long long baseElem = rowBase * 11;                // float index of block chunk
    const long long totalElem = (long long)B * 11;

    // ---- stage 512 rows (5632 floats = 22528B) into LDS, minimal-request ----
    __shared__ float lds[RPB * 11];
#pragma unroll
    for (int k = 0; k < 6; ++k) {                 // 1408 float4 chunks / 256 threads
        const int c = tid + k * BLOCK;
        if (c < (RPB * 11) / 4) {
            const long long e = baseElem + 4LL * c;   // 16B-aligned (base 16B, 4|e)
            float4 v;
            if (e + 4 <= totalElem) {
                v = *reinterpret_cast<const float4*>(x + e);
            } else {                               // guarded tail (last block only)
                v.x = (e + 0 < totalElem) ? x[e + 0] : 0.0f;
                v.y = (e + 1 < totalElem) ? x[e + 1] : 0.0f;
                v.z = (e + 2 < totalElem) ? x[e + 2] : 0.0f;
                v.w = (e + 3 < totalElem) ? x[e + 3] : 0.0f;
            }
            *reinterpret_cast<float4*>(&lds[4 * c]) = v;
        }
    }
    __syncthreads();

    // ---- gather this thread's adjacent row pair: ds_read2_b32 pattern ----
    const long long rowA = rowBase + 2 * tid;     // even
    const long long rowB = rowA + 1;
    const int l0 = 22 * tid;                      // dword offset of row pair
    v2f xin[11];
#pragma unroll
    for (int c = 0; c < 11; ++c) {
        xin[c].x = lds[l0 + c];                   // row A, col c
        xin[c].y = lds[l0 + 11 + c];              // row B, col c
    }

    // ---- f_up: [f, fd] -> 2 -> 2 ----
    v2f fin[2] = {xin[4], xin[10]};
    v2f tf[2], f_up[2];
    lin2<2,2,true>(fin, tf, P.w[FU1], P.b[FU1]);
    lin2<2,2,true>(tf, f_up, P.w[FU2], P.b[FU2]);

    // ---- k_up: [k, kd, f_up] -> 4 -> 4 ----
    v2f kin[4] = {xin[3], xin[9], f_up[0], f_up[1]};
    v2f tk[4], k_up[4];
    lin2<4,4,true>(kin, tk, P.w[KU1], P.b[KU1]);
    lin2<4,4,true>(tk, k_up, P.w[KU2], P.b[KU2]);

    // ---- h_up: [h, hd, k_up] -> 6 -> 6 ----
    v2f hin[6] = {xin[2], xin[8], k_up[0], k_up[1], k_up[2], k_up[3]};
    v2f th[6], h_up[6];
    lin2<6,6,true>(hin, th, P.w[HU1], P.b[HU1]);
    lin2<6,6,true>(th, h_up, P.w[HU2], P.b[HU2]);

    // ---- m_down: [m_obs(5), h_up(6)] -> 16 -> 16 -> 6 ----
    v2f min_[11] = {xin[0], xin[1], xin[5], xin[6], xin[7],
                    h_up[0], h_up[1], h_up[2], h_up[3], h_up[4], h_up[5]};
    v2f t16a[16], t16b[16], m_down[6];
    lin2<11,16,true>(min_, t16a, P.w[MD1], P.b[MD1]);
    lin2<16,16,true>(t16a, t16b, P.w[MD2], P.b[MD2]);
    lin2<16,6,true>(t16b, m_down, P.w[MD3], P.b[MD3]);

    // ---- h_down: m_down -> 4 -> 4 ----
    v2f t4b[4], h_down[4];
    lin2<6,4,true>(m_down, t4b, P.w[HD1], P.b[HD1]);
    lin2<4,4,true>(t4b, h_down, P.w[HD2], P.b[HD2]);

    // ---- k_down: h_down -> 2 -> 2 ----
    v2f t2b[2], k_down[2];
    lin2<4,2,true>(h_down, t2b, P.w[KD1], P.b[KD1]);
    lin2<2,2,true>(t2b, k_down, P.w[KD2], P.b[KD2]);

    // ---- h_act: [h, hd, m_down(6)] -> 4 -> 1 (no relu on last) ----
    v2f ha_in[8] = {xin[2], xin[8], m_down[0], m_down[1],
                    m_down[2], m_down[3], m_down[4], m_down[5]};
    v2f t4c[4], h_act[1];
    lin2<8,4,true>(ha_in, t4c, P.w[HA1], P.b[HA1]);
    lin2<4,1,false>(t4c, h_act, P.w[HA2], P.b[HA2]);   // acc pair = {rowA, rowB}

    // ---- k_act: [k, kd, h_down(4)] -> 4 -> 1 ----
    v2f ka_in[6] = {xin[3], xin[9], h_down[0], h_down[1], h_down[2], h_down[3]};
    v2f t4d[4], k_act[1];
    lin2<6,4,true>(ka_in, t4d, P.w[KA1], P.b[KA1]);
    lin2<4,1,false>(t4d, k_act, P.w[KA2], P.b[KA2]);

    // ---- f_act: [f, fd, k_down(2)] -> 4 -> 1 ----
    v2f fa_in[4] = {xin[4], xin[10], k_down[0], k_down[1]};
    v2f t4e[4], f_act[1];
    lin2<4,4,true>(fa_in, t4e, P.w[FA1], P.b[FA1]);
    lin2<4,1,false>(t4e, f_act, P.w[FA2], P.b[FA2]);

    // ---- store: adjacent rows -> 6 contiguous floats -> 3 aligned float2 ----
    if (rowB < B) {
        float* po = out + rowA * 3;               // byte offset 24*tid: 8-aligned
        float2 s0 = {h_act[0].x, f_act[0].x};
        float2 s1 = {k_act[0].x, h_act[0].y};
        float2 s2 = {f_act[0].y, k_act[0].y};
        *reinterpret_cast<float2*>(po + 0) = s0;
        *reinterpret_cast<float2*>(po + 2) = s1;
        *reinterpret_cast<float2*>(po + 4) = s2;
    } else if (rowA < B) {                        // odd-B tail: single row
        float* po = out + rowA * 3;
        po[0] = h_act[0].x;
        po[1] = f_act[0].x;
        po[2] = k_act[0].x;
    }
}

extern "C" void kernel_launch(void* const* d_in, const int* in_sizes, int n_in,
                              void* d_out, int out_size, void* d_ws, size_t ws_size,
                              hipStream_t stream) {
    static const int wn[19] = {4,4,16,16,36,36,176,256,96,24,16,8,4,32,4,24,4,16,4};
    static const int bn[19] = {2,2,4,4,6,6,16,16,6,4,4,2,2,4,1,4,1,4,1};

    const float* x = (const float*)d_in[0];
    float* out = (float*)d_out;
    const int B = in_sizes[0] / 11;

    WPtrs P;
    for (int i = 0; i < 19; ++i) {
        P.w[i] = (const float*)d_in[1 + 2*i];
        P.b[i] = (const float*)d_in[2 + 2*i];
    }

    float* ws = (float*)d_ws;
    WDup D;
    int off = 0;
    for (int l = 0; l < 19; ++l) {
        D.w[l] = (const v2f*)(ws + off); off += 2 * wn[l];
        D.b[l] = (const v2f*)(ws + off); off += 2 * bn[l];
    }

    prep_kernel<<<19, BLOCK, 0, stream>>>(P, ws);   // one block per layer, ~2 us

    const int blocks = (int)(((long long)B + RPB - 1) / RPB);
    pnet_kernel<<<blocks, BLOCK, 0, stream>>>(x, out, B, D);
}

// Round 9
// 238.932 us; speedup vs baseline: 1.0159x; 1.0159x over previous
//
#include <hip/hip_runtime.h>

#define BLOCK 256
// R9: single-variable change vs the proven R3 body (55.6us, VGPR=40, zero
// scratch): weights move from the SCALAR pipe to LDS.
// Evidence: R3/R6/R8 all show ~27us busy + ~29-41us stall; the stall ignored
// ILP changes (R6), input coalescing (R8), persistence (R5). Remaining stream:
// 1681 dup-weight dwords/wave via s_load with a ~104-SGPR budget -> ~50 small
// chunks each with an lgkmcnt wait; chunks serialize and all waves stall at
// the same boundaries (R8's barrier-lockstep made it worse).
// Fix: block start copies the 6920B dup table into LDS (865 float2, 4
// coalesced iters); every weight/bias is then ds_read_b64 at a COMPILE-TIME
// immediate offset (zero addr math, uniform-address broadcast = conflict-free,
// deep outstanding queue, per-CU BW). Scalar pipe freed; input loads issued
// before the copy so they overlap.
// FMA stream unchanged: packed v2f, {w,w} pair operand (legal VOP3P src;
// R7 proved a lone 32-bit SGPR is not). Locals stay in the <=16-element
// constant-indexed SROA class (R1/R4: bigger -> scratch).

typedef float v2f __attribute__((ext_vector_type(2)));

struct WPtrs {
    const float* w[19];
    const float* b[19];
};

enum LId {FU1,FU2,KU1,KU2,HU1,HU2,MD1,MD2,MD3,HD1,HD2,KD1,KD2,HA1,HA2,KA1,KA2,FA1,FA2};

__constant__ const int kWN[19] = {4,4,16,16,36,36,176,256,96,24,16,8,4,32,4,24,4,16,4};
__constant__ const int kBN[19] = {2,2,4,4,6,6,16,16,6,4,4,2,2,4,1,4,1,4,1};

// ---- prep: duplicate weights+biases into ws as {v,v}; one block per layer ----
__global__ void prep_kernel(WPtrs P, float* __restrict__ ws) {
    const int l = blockIdx.x;
    const int t = threadIdx.x;
    int off = 0;
    for (int i = 0; i < l; ++i) off += 2 * (kWN[i] + kBN[i]);
    float* dw = ws + off;
    const int wn = kWN[l];
    for (int i = t; i < wn; i += BLOCK) {
        const float v = P.w[l][i];
        dw[2*i] = v; dw[2*i+1] = v;
    }
    float* db = dw + 2*wn;
    const int bn = kBN[l];
    for (int i = t; i < bn; i += BLOCK) {
        const float v = P.b[l][i];
        db[2*i] = v; db[2*i+1] = v;
    }
}

// v2f-unit offsets of each layer's w and b inside the dup table (cumulative
// over the prep layout: [w_l][b_l] per layer).
#define WO_FU1 0
#define BO_FU1 4
#define WO_FU2 6
#define BO_FU2 10
#define WO_KU1 12
#define BO_KU1 28
#define WO_KU2 32
#define BO_KU2 48
#define WO_HU1 52
#define BO_HU1 88
#define WO_HU2 94
#define BO_HU2 130
#define WO_MD1 136
#define BO_MD1 312
#define WO_MD2 328
#define BO_MD2 584
#define WO_MD3 600
#define BO_MD3 696
#define WO_HD1 702
#define BO_HD1 726
#define WO_HD2 730
#define BO_HD2 746
#define WO_KD1 750
#define BO_KD1 758
#define WO_KD2 760
#define BO_KD2 764
#define WO_HA1 766
#define BO_HA1 798
#define WO_HA2 802
#define BO_HA2 806
#define WO_KA1 807
#define BO_KA1 831
#define WO_KA2 835
#define BO_KA2 839
#define WO_FA1 840
#define BO_FA1 856
#define WO_FA2 860
#define BO_FA2 864
#define NDUP   865

template<int DIN,int DOUT,bool RELU>
__device__ __forceinline__ void lin2(const v2f (&in)[DIN], v2f (&out)[DOUT],
                                     const v2f* wd, const v2f* bd) {
#pragma unroll
    for (int j = 0; j < DOUT; ++j) {
        v2f acc = bd[j];                          // ds_read_b64, imm offset
#pragma unroll
        for (int i = 0; i < DIN; ++i)
            acc = __builtin_elementwise_fma(in[i], wd[i*DOUT + j], acc); // v_pk_fma_f32
        if (RELU) {
            const v2f z = {0.0f, 0.0f};
            acc = __builtin_elementwise_max(acc, z);                     // v_pk_max_f32
        }
        out[j] = acc;
    }
}

__global__ __launch_bounds__(BLOCK) void pnet_kernel(
    const float* __restrict__ x, float* __restrict__ out, int B,
    const float* __restrict__ wdup) {
    __shared__ v2f wsh[NDUP];
    const int tid  = threadIdx.x;
    const int rowA = blockIdx.x * (BLOCK * 2) + tid;
    const int rowB = rowA + BLOCK;

    // ---- issue input loads first so they overlap the LDS weight fill ----
    const int rA = rowA < B ? rowA : (B - 1);   // clamp loads; stores guarded below
    const int rB = rowB < B ? rowB : (B - 1);
    const float* pA = x + (long long)rA * 11;
    const float* pB = x + (long long)rB * 11;
    v2f xin[11];
#pragma unroll
    for (int c = 0; c < 11; ++c) { xin[c].x = pA[c]; xin[c].y = pB[c]; }

    // ---- copy dup table into LDS: 865 float2, coalesced, 4 iters ----
    {
        float2* dst = reinterpret_cast<float2*>(wsh);
        const float2* src = reinterpret_cast<const float2*>(wdup);
        for (int i = tid; i < NDUP; i += BLOCK) dst[i] = src[i];
    }
    __syncthreads();

    // ---- f_up: [f, fd] -> 2 -> 2 ----
    v2f fin[2] = {xin[4], xin[10]};
    v2f tf[2], f_up[2];
    lin2<2,2,true>(fin, tf, &wsh[WO_FU1], &wsh[BO_FU1]);
    lin2<2,2,true>(tf, f_up, &wsh[WO_FU2], &wsh[BO_FU2]);

    // ---- k_up: [k, kd, f_up] -> 4 -> 4 ----
    v2f kin[4] = {xin[3], xin[9], f_up[0], f_up[1]};
    v2f tk[4], k_up[4];
    lin2<4,4,true>(kin, tk, &wsh[WO_KU1], &wsh[BO_KU1]);
    lin2<4,4,true>(tk, k_up, &wsh[WO_KU2], &wsh[BO_KU2]);

    // ---- h_up: [h, hd, k_up] -> 6 -> 6 ----
    v2f hin[6] = {xin[2], xin[8], k_up[0], k_up[1], k_up[2], k_up[3]};
    v2f th[6], h_up[6];
    lin2<6,6,true>(hin, th, &wsh[WO_HU1], &wsh[BO_HU1]);
    lin2<6,6,true>(th, h_up, &wsh[WO_HU2], &wsh[BO_HU2]);

    // ---- m_down: [m_obs(5), h_up(6)] -> 16 -> 16 -> 6 ----
    v2f min_[11] = {xin[0], xin[1], xin[5], xin[6], xin[7],
                    h_up[0], h_up[1], h_up[2], h_up[3], h_up[4], h_up[5]};
    v2f t16a[16], t16b[16], m_down[6];
    lin2<11,16,true>(min_, t16a, &wsh[WO_MD1], &wsh[BO_MD1]);
    lin2<16,16,true>(t16a, t16b, &wsh[WO_MD2], &wsh[BO_MD2]);
    lin2<16,6,true>(t16b, m_down, &wsh[WO_MD3], &wsh[BO_MD3]);

    // ---- h_down: m_down -> 4 -> 4 ----
    v2f t4b[4], h_down[4];
    lin2<6,4,true>(m_down, t4b, &wsh[WO_HD1], &wsh[BO_HD1]);
    lin2<4,4,true>(t4b, h_down, &wsh[WO_HD2], &wsh[BO_HD2]);

    // ---- k_down: h_down -> 2 -> 2 ----
    v2f t2b[2], k_down[2];
    lin2<4,2,true>(h_down, t2b, &wsh[WO_KD1], &wsh[BO_KD1]);
    lin2<2,2,true>(t2b, k_down, &wsh[WO_KD2], &wsh[BO_KD2]);

    // ---- h_act: [h, hd, m_down(6)] -> 4 -> 1 (no relu on last) ----
    v2f ha_in[8] = {xin[2], xin[8], m_down[0], m_down[1],
                    m_down[2], m_down[3], m_down[4], m_down[5]};
    v2f t4c[4], h_act[1];
    lin2<8,4,true>(ha_in, t4c, &wsh[WO_HA1], &wsh[BO_HA1]);
    lin2<4,1,false>(t4c, h_act, &wsh[WO_HA2], &wsh[BO_HA2]);  // acc = {rowA,rowB}

    // ---- k_act: [k, kd, h_down(4)] -> 4 -> 1 ----
    v2f ka_in[6] = {xin[3], xin[9], h_down[0], h_down[1], h_down[2], h_down[3]};
    v2f t4d[4], k_act[1];
    lin2<6,4,true>(ka_in, t4d, &wsh[WO_KA1], &wsh[BO_KA1]);
    lin2<4,1,false>(t4d, k_act, &wsh[WO_KA2], &wsh[BO_KA2]);

    // ---- f_act: [f, fd, k_down(2)] -> 4 -> 1 ----
    v2f fa_in[4] = {xin[4], xin[10], k_down[0], k_down[1]};
    v2f t4e[4], f_act[1];
    lin2<4,4,true>(fa_in, t4e, &wsh[WO_FA1], &wsh[BO_FA1]);
    lin2<4,1,false>(t4e, f_act, &wsh[WO_FA2], &wsh[BO_FA2]);

    // ---- store: [h_act, f_act, k_act] per row (guarded for tail) ----
    if (rowA < B) {
        float* po = out + (long long)rowA * 3;
        po[0] = h_act[0].x;
        po[1] = f_act[0].x;
        po[2] = k_act[0].x;
    }
    if (rowB < B) {
        float* po = out + (long long)rowB * 3;
        po[0] = h_act[0].y;
        po[1] = f_act[0].y;
        po[2] = k_act[0].y;
    }
}

extern "C" void kernel_launch(void* const* d_in, const int* in_sizes, int n_in,
                              void* d_out, int out_size, void* d_ws, size_t ws_size,
                              hipStream_t stream) {
    const float* x = (const float*)d_in[0];
    float* out = (float*)d_out;
    const int B = in_sizes[0] / 11;

    WPtrs P;
    for (int i = 0; i < 19; ++i) {
        P.w[i] = (const float*)d_in[1 + 2*i];
        P.b[i] = (const float*)d_in[2 + 2*i];
    }

    float* ws = (float*)d_ws;
    prep_kernel<<<19, BLOCK, 0, stream>>>(P, ws);   // one block per layer, ~2 us

    const long long rows_per_block = (long long)BLOCK * 2;
    const int blocks = (int)((B + rows_per_block - 1) / rows_per_block);
    pnet_kernel<<<blocks, BLOCK, 0, stream>>>(x, out, B, ws);
}

// Round 10
// 229.423 us; speedup vs baseline: 1.0580x; 1.0414x over previous
//
#include <hip/hip_runtime.h>

#define BLOCK 256
// R10: j-packed VOP3P. Evidence ledger: busy ~27us invariant (R3/R6/R8);
// stall tracks scalar weight dwords (R0: 819dw->21us, R3 dup: 1681dw->29us);
// LDS-uniform delivery worse (R9: 8B/inst); VGPR-lane delivery worse (R5:
// readlane). So: keep scalar s_load delivery, halve it back to 819 dwords by
// packing the vector dim over OUTPUT PAIRS (j,j+1) of each row instead of
// over rows. Weight pair {w[i][j],w[i][j+1]} is then naturally contiguous ->
// s_load_dwordx2 SGPR pair, NO dup table, NO prep kernel. The {x_i,x_i}
// broadcast is done by the INSTRUCTION via op_sel/op_sel_hi on a legal
// 64-bit src pair (R7's failure was a 32-bit operand, not op_sel itself):
//   rowA: op_sel:[0,0,0] op_sel_hi:[0,1,1]  (lo half of src0 -> both halves)
//   rowB: op_sel:[1,0,0] op_sel_hi:[1,1,1]  (hi half -> both halves)
// Same 776-pk_fma stream as R3 (busy unchanged). Heads (DOUT=1) scalar fmac.
// Locals stay <=16-element constant-indexed (R1/R4: bigger -> scratch).

typedef float v2f __attribute__((ext_vector_type(2)));
typedef unsigned long long u64;

struct WPtrs {
    const float* w[19];
    const float* b[19];
};

enum LId {FU1,FU2,KU1,KU2,HU1,HU2,MD1,MD2,MD3,HD1,HD2,KD1,KD2,HA1,HA2,KA1,KA2,FA1,FA2};

// acc.{lo,hi} += s.lo * w.{lo,hi}   (broadcast LO of src0 pair)
__device__ __forceinline__ void fmaL(v2f& acc, const v2f s, const u64 w) {
    asm("v_pk_fma_f32 %0, %1, %2, %0 op_sel:[0,0,0] op_sel_hi:[0,1,1]"
        : "+v"(acc) : "v"(s), "s"(w));
}
// acc.{lo,hi} += s.hi * w.{lo,hi}   (broadcast HI of src0 pair)
__device__ __forceinline__ void fmaH(v2f& acc, const v2f s, const u64 w) {
    asm("v_pk_fma_f32 %0, %1, %2, %0 op_sel:[1,0,0] op_sel_hi:[1,1,1]"
        : "+v"(acc) : "v"(s), "s"(w));
}

__device__ __forceinline__ v2f pkmax0(const v2f a) {
    const v2f z = {0.0f, 0.0f};
    return __builtin_elementwise_max(a, z);
}
__device__ __forceinline__ v2f bias2(const float* b, int jp) {
    return *reinterpret_cast<const v2f*>(b + 2*jp);
}

// Layer whose inputs are ALL j-packed pairs of the same row (both rows done).
// w row-major [2*DINP][2*DOUTP]; u64 index of elem i, outpair jp = i*DOUTP+jp.
template<int DINP,int DOUTP,bool RELU>
__device__ __forceinline__ void linP(const v2f (&inA)[DINP], const v2f (&inB)[DINP],
                                     v2f (&oA)[DOUTP], v2f (&oB)[DOUTP],
                                     const float* __restrict__ w,
                                     const float* __restrict__ b) {
    const u64* wp = reinterpret_cast<const u64*>(w);
#pragma unroll
    for (int jp = 0; jp < DOUTP; ++jp) {
        v2f aA = bias2(b, jp);
        v2f aB = aA;
#pragma unroll
        for (int ip = 0; ip < DINP; ++ip) {
            const u64 w0 = wp[(2*ip)   * DOUTP + jp];
            const u64 w1 = wp[(2*ip+1) * DOUTP + jp];
            fmaL(aA, inA[ip], w0); fmaL(aB, inB[ip], w0);
            fmaH(aA, inA[ip], w1); fmaH(aB, inB[ip], w1);
        }
        oA[jp] = RELU ? pkmax0(aA) : aA;
        oB[jp] = RELU ? pkmax0(aB) : aB;
    }
}

// Head: DIN=4 (two j-pairs), DOUT=1, no relu. Scalar fmac, SGPR weights.
__device__ __forceinline__ void head(const v2f (&inA)[2], const v2f (&inB)[2],
                                     float& oA, float& oB,
                                     const float* __restrict__ w,
                                     const float* __restrict__ b) {
    float aA = b[0], aB = b[0];
    aA = __builtin_fmaf(inA[0].x, w[0], aA); aB = __builtin_fmaf(inB[0].x, w[0], aB);
    aA = __builtin_fmaf(inA[0].y, w[1], aA); aB = __builtin_fmaf(inB[0].y, w[1], aB);
    aA = __builtin_fmaf(inA[1].x, w[2], aA); aB = __builtin_fmaf(inB[1].x, w[2], aB);
    aA = __builtin_fmaf(inA[1].y, w[3], aA); aB = __builtin_fmaf(inB[1].y, w[3], aB);
    oA = aA; oB = aB;
}

__global__ __launch_bounds__(BLOCK) void pnet_kernel(
    const float* __restrict__ x, float* __restrict__ out, int B, WPtrs P) {
    const int tid  = threadIdx.x;
    const int rowA = blockIdx.x * (BLOCK * 2) + tid;
    const int rowB = rowA + BLOCK;

    const int rA = rowA < B ? rowA : (B - 1);   // clamp loads; stores guarded below
    const int rB = rowB < B ? rowB : (B - 1);
    const float* pA = x + (long long)rA * 11;
    const float* pB = x + (long long)rB * 11;
    v2f xin[11];                                 // {rowA_c, rowB_c}
#pragma unroll
    for (int c = 0; c < 11; ++c) { xin[c].x = pA[c]; xin[c].y = pB[c]; }

    // ---- fu1: [f, fd] -> 2 (1 pair) ----
    v2f fA1[1], fB1[1];
    {
        const u64* wp = reinterpret_cast<const u64*>(P.w[FU1]);
        v2f aA = bias2(P.b[FU1], 0), aB = aA;
        fmaL(aA, xin[4],  wp[0]); fmaH(aB, xin[4],  wp[0]);
        fmaL(aA, xin[10], wp[1]); fmaH(aB, xin[10], wp[1]);
        fA1[0] = pkmax0(aA); fB1[0] = pkmax0(aB);
    }
    // ---- fu2: 2 -> 2 ----
    v2f fA2[1], fB2[1];
    linP<1,1,true>(fA1, fB1, fA2, fB2, P.w[FU2], P.b[FU2]);

    // ---- ku1: [k, kd, f_up(2)] -> 4 (2 pairs) ----
    v2f kA1[2], kB1[2];
    {
        const u64* wp = reinterpret_cast<const u64*>(P.w[KU1]);
#pragma unroll
        for (int jp = 0; jp < 2; ++jp) {
            v2f aA = bias2(P.b[KU1], jp), aB = aA;
            fmaL(aA, xin[3], wp[0*2+jp]); fmaH(aB, xin[3], wp[0*2+jp]);
            fmaL(aA, xin[9], wp[1*2+jp]); fmaH(aB, xin[9], wp[1*2+jp]);
            fmaL(aA, fA2[0], wp[2*2+jp]); fmaL(aB, fB2[0], wp[2*2+jp]);
            fmaH(aA, fA2[0], wp[3*2+jp]); fmaH(aB, fB2[0], wp[3*2+jp]);
            kA1[jp] = pkmax0(aA); kB1[jp] = pkmax0(aB);
        }
    }
    // ---- ku2: 4 -> 4 ----
    v2f kA2[2], kB2[2];
    linP<2,2,true>(kA1, kB1, kA2, kB2, P.w[KU2], P.b[KU2]);

    // ---- hu1: [h, hd, k_up(4)] -> 6 (3 pairs) ----
    v2f hA1[3], hB1[3];
    {
        const u64* wp = reinterpret_cast<const u64*>(P.w[HU1]);
#pragma unroll
        for (int jp = 0; jp < 3; ++jp) {
            v2f aA = bias2(P.b[HU1], jp), aB = aA;
            fmaL(aA, xin[2], wp[0*3+jp]); fmaH(aB, xin[2], wp[0*3+jp]);
            fmaL(aA, xin[8], wp[1*3+jp]); fmaH(aB, xin[8], wp[1*3+jp]);
            fmaL(aA, kA2[0], wp[2*3+jp]); fmaL(aB, kB2[0], wp[2*3+jp]);
            fmaH(aA, kA2[0], wp[3*3+jp]); fmaH(aB, kB2[0], wp[3*3+jp]);
            fmaL(aA, kA2[1], wp[4*3+jp]); fmaL(aB, kB2[1], wp[4*3+jp]);
            fmaH(aA, kA2[1], wp[5*3+jp]); fmaH(aB, kB2[1], wp[5*3+jp]);
            hA1[jp] = pkmax0(aA); hB1[jp] = pkmax0(aB);
        }
    }
    // ---- hu2: 6 -> 6 ----
    v2f hA2[3], hB2[3];
    linP<3,3,true>(hA1, hB1, hA2, hB2, P.w[HU2], P.b[HU2]);

    // ---- md1: [m_obs(5), h_up(6)] -> 16 (8 pairs) ----
    v2f mA1[8], mB1[8];
    {
        const u64* wp = reinterpret_cast<const u64*>(P.w[MD1]);
#pragma unroll
        for (int jp = 0; jp < 8; ++jp) {
            v2f aA = bias2(P.b[MD1], jp), aB = aA;
            fmaL(aA, xin[0], wp[0*8+jp]);  fmaH(aB, xin[0], wp[0*8+jp]);
            fmaL(aA, xin[1], wp[1*8+jp]);  fmaH(aB, xin[1], wp[1*8+jp]);
            fmaL(aA, xin[5], wp[2*8+jp]);  fmaH(aB, xin[5], wp[2*8+jp]);
            fmaL(aA, xin[6], wp[3*8+jp]);  fmaH(aB, xin[6], wp[3*8+jp]);
            fmaL(aA, xin[7], wp[4*8+jp]);  fmaH(aB, xin[7], wp[4*8+jp]);
            fmaL(aA, hA2[0], wp[5*8+jp]);  fmaL(aB, hB2[0], wp[5*8+jp]);
            fmaH(aA, hA2[0], wp[6*8+jp]);  fmaH(aB, hB2[0], wp[6*8+jp]);
            fmaL(aA, hA2[1], wp[7*8+jp]);  fmaL(aB, hB2[1], wp[7*8+jp]);
            fmaH(aA, hA2[1], wp[8*8+jp]);  fmaH(aB, hB2[1], wp[8*8+jp]);
            fmaL(aA, hA2[2], wp[9*8+jp]);  fmaL(aB, hB2[2], wp[9*8+jp]);
            fmaH(aA, hA2[2], wp[10*8+jp]); fmaH(aB, hB2[2], wp[10*8+jp]);
            mA1[jp] = pkmax0(aA); mB1[jp] = pkmax0(aB);
        }
    }
    // ---- md2: 16 -> 16 ----
    v2f mA2[8], mB2[8];
    linP<8,8,true>(mA1, mB1, mA2, mB2, P.w[MD2], P.b[MD2]);
    // ---- md3: 16 -> 6 ----
    v2f mA3[3], mB3[3];
    linP<8,3,true>(mA2, mB2, mA3, mB3, P.w[MD3], P.b[MD3]);

    // ---- hd1: 6 -> 4 ----
    v2f dA1[2], dB1[2];
    linP<3,2,true>(mA3, mB3, dA1, dB1, P.w[HD1], P.b[HD1]);
    // ---- hd2: 4 -> 4 ----
    v2f dA2[2], dB2[2];
    linP<2,2,true>(dA1, dB1, dA2, dB2, P.w[HD2], P.b[HD2]);

    // ---- kd1: 4 -> 2 ----
    v2f eA1[1], eB1[1];
    linP<2,1,true>(dA2, dB2, eA1, eB1, P.w[KD1], P.b[KD1]);
    // ---- kd2: 2 -> 2 ----
    v2f eA2[1], eB2[1];
    linP<1,1,true>(eA1, eB1, eA2, eB2, P.w[KD2], P.b[KD2]);

    // ---- ha1: [h, hd, m_down(6)] -> 4 (2 pairs) ----
    v2f gA[2], gB[2];
    {
        const u64* wp = reinterpret_cast<const u64*>(P.w[HA1]);
#pragma unroll
        for (int jp = 0; jp < 2; ++jp) {
            v2f aA = bias2(P.b[HA1], jp), aB = aA;
            fmaL(aA, xin[2], wp[0*2+jp]); fmaH(aB, xin[2], wp[0*2+jp]);
            fmaL(aA, xin[8], wp[1*2+jp]); fmaH(aB, xin[8], wp[1*2+jp]);
            fmaL(aA, mA3[0], wp[2*2+jp]); fmaL(aB, mB3[0], wp[2*2+jp]);
            fmaH(aA, mA3[0], wp[3*2+jp]); fmaH(aB, mB3[0], wp[3*2+jp]);
            fmaL(aA, mA3[1], wp[4*2+jp]); fmaL(aB, mB3[1], wp[4*2+jp]);
            fmaH(aA, mA3[1], wp[5*2+jp]); fmaH(aB, mB3[1], wp[5*2+jp]);
            fmaL(aA, mA3[2], wp[6*2+jp]); fmaL(aB, mB3[2], wp[6*2+jp]);
            fmaH(aA, mA3[2], wp[7*2+jp]); fmaH(aB, mB3[2], wp[7*2+jp]);
            gA[jp] = pkmax0(aA); gB[jp] = pkmax0(aB);
        }
    }
    // ---- ha2: 4 -> 1 ----
    float h_actA, h_actB;
    head(gA, gB, h_actA, h_actB, P.w[HA2], P.b[HA2]);

    // ---- ka1: [k, kd, h_down(4)] -> 4 (2 pairs) ----
    v2f qA[2], qB[2];
    {
        const u64* wp = reinterpret_cast<const u64*>(P.w[KA1]);
#pragma unroll
        for (int jp = 0; jp < 2; ++jp) {
            v2f aA = bias2(P.b[KA1], jp), aB = aA;
            fmaL(aA, xin[3], wp[0*2+jp]); fmaH(aB, xin[3], wp[0*2+jp]);
            fmaL(aA, xin[9], wp[1*2+jp]); fmaH(aB, xin[9], wp[1*2+jp]);
            fmaL(aA, dA2[0], wp[2*2+jp]); fmaL(aB, dB2[0], wp[2*2+jp]);
            fmaH(aA, dA2[0], wp[3*2+jp]); fmaH(aB, dB2[0], wp[3*2+jp]);
            fmaL(aA, dA2[1], wp[4*2+jp]); fmaL(aB, dB2[1], wp[4*2+jp]);
            fmaH(aA, dA2[1], wp[5*2+jp]); fmaH(aB, dB2[1], wp[5*2+jp]);
            qA[jp] = pkmax0(aA); qB[jp] = pkmax0(aB);
        }
    }
    // ---- ka2: 4 -> 1 ----
    float k_actA, k_actB;
    head(qA, qB, k_actA, k_actB, P.w[KA2], P.b[KA2]);

    // ---- fa1: [f, fd, k_down(2)] -> 4 (2 pairs) ----
    v2f rA2[2], rB2[2];
    {
        const u64* wp = reinterpret_cast<const u64*>(P.w[FA1]);
#pragma unroll
        for (int jp = 0; jp < 2; ++jp) {
            v2f aA = bias2(P.b[FA1], jp), aB = aA;
            fmaL(aA, xin[4],  wp[0*2+jp]); fmaH(aB, xin[4],  wp[0*2+jp]);
            fmaL(aA, xin[10], wp[1*2+jp]); fmaH(aB, xin[10], wp[1*2+jp]);
            fmaL(aA, eA2[0],  wp[2*2+jp]); fmaL(aB, eB2[0],  wp[2*2+jp]);
            fmaH(aA, eA2[0],  wp[3*2+jp]); fmaH(aB, eB2[0],  wp[3*2+jp]);
            rA2[jp] = pkmax0(aA); rB2[jp] = pkmax0(aB);
        }
    }
    // ---- fa2: 4 -> 1 ----
    float f_actA, f_actB;
    head(rA2, rB2, f_actA, f_actB, P.w[FA2], P.b[FA2]);

    // ---- store: [h_act, f_act, k_act] per row (guarded for tail) ----
    if (rowA < B) {
        float* po = out + (long long)rowA * 3;
        po[0] = h_actA; po[1] = f_actA; po[2] = k_actA;
    }
    if (rowB < B) {
        float* po = out + (long long)rowB * 3;
        po[0] = h_actB; po[1] = f_actB; po[2] = k_actB;
    }
}

extern "C" void kernel_launch(void* const* d_in, const int* in_sizes, int n_in,
                              void* d_out, int out_size, void* d_ws, size_t ws_size,
                              hipStream_t stream) {
    const float* x = (const float*)d_in[0];
    float* out = (float*)d_out;
    const int B = in_sizes[0] / 11;

    WPtrs P;
    for (int i = 0; i < 19; ++i) {
        P.w[i] = (const float*)d_in[1 + 2*i];
        P.b[i] = (const float*)d_in[2 + 2*i];
    }

    const long long rows_per_block = (long long)BLOCK * 2;
    const int blocks = (int)((B + rows_per_block - 1) / rows_per_block);
    pnet_kernel<<<blocks, BLOCK, 0, stream>>>(x, out, B, P);
}